// Round 8
// baseline (628.567 us; speedup 1.0000x reference)
//
#include <hip/hip_runtime.h>
#include <math.h>

static constexpr int BROWS   = 16384;
static constexpr int NC      = 784;
static constexpr int TRB     = 16;              // rows per block
static constexpr int NBLK    = BROWS / TRB;     // 1024 blocks
static constexpr int NREP    = 4;               // replicated stat accumulators
static constexpr float EPS   = 1e-5f;
static constexpr float INV_B = 1.0f / (float)BROWS;

// persistent-kernel geometry: 256 thr, 4 slots; LDS 31.4KB, VGPR<=128 -> 4 blocks/CU
// -> capacity 256CU*4 = 1024 = grid (cooperative launch guarantees co-residency).
static constexpr int PTHREADS = 256;
static constexpr int PNSLOT   = 4;
// fallback (proven 185us 4-kernel pipeline) geometry
static constexpr int FTHREADS = 512;
static constexpr int FNSLOT   = 2;

#if defined(__has_builtin)
#if __has_builtin(__builtin_amdgcn_global_load_lds)
#define HAVE_ASYNC_LDS 1
#endif
#if __has_builtin(__builtin_amdgcn_rcpf)
#define HAVE_RCPF 1
#endif
#if __has_builtin(__builtin_elementwise_fma)
#define HAVE_EW_FMA 1
#endif
#endif

typedef float v2f __attribute__((ext_vector_type(2)));

__device__ __forceinline__ void stage16(const float4* g, float4* l) {
#ifdef HAVE_ASYNC_LDS
    __builtin_amdgcn_global_load_lds(
        (const __attribute__((address_space(1))) void*)g,
        (__attribute__((address_space(3))) void*)l, 16, 0, 0);
#else
    *l = *g;
#endif
}

// ---- bf16 helpers (raw u16 storage; RNE convert) ----
__device__ __forceinline__ unsigned short f2b(float f) {
    union { float f; unsigned u; } v; v.f = f;
    const unsigned r = v.u + 0x7fffu + ((v.u >> 16) & 1u);
    return (unsigned short)(r >> 16);
}
__device__ __forceinline__ unsigned pack2(float lo, float hi) {
    return (unsigned)f2b(lo) | ((unsigned)f2b(hi) << 16);
}
__device__ __forceinline__ unsigned long long pack4(float a, float b, float c, float d) {
    return (unsigned long long)pack2(a, b) | ((unsigned long long)pack2(c, d) << 32);
}
__device__ __forceinline__ unsigned long long pack_f2(float a, float b) {
    union { float f[2]; unsigned long long u; } v; v.f[0] = a; v.f[1] = b; return v.u;
}
__device__ __forceinline__ void unpack_f2(unsigned long long u, float& a, float& b) {
    union { float f[2]; unsigned long long u; } v; v.u = u; a = v.f[0]; b = v.f[1];
}
__device__ __forceinline__ float fast_rcp(float x) {
#ifdef HAVE_RCPF
    return __builtin_amdgcn_rcpf(x);
#else
    return 1.0f / x;
#endif
}

// tanh-form gelu (max |err| ~3e-4, far under the 0.2625 budget), branchless.
__device__ __forceinline__ float gelu_f(float x) {
    const float u  = x * x;
    const float z  = x * fmaf(0.0356774081f, u, 0.7978845608f);
    const float e  = __expf(2.0f * z);
    const float r  = fast_rcp(e + 1.0f);
    const float t  = fmaf(-2.0f, r, 1.0f);
    const float hx = 0.5f * x;
    return fmaf(hx, t, hx);
}

// u64 = 4 bf16 rows of one column (rows 4q..4q+3) -> 2x packed FMA.
__device__ __forceinline__ void fmaq(const unsigned long long v, const float w, v2f acc[2]) {
    const unsigned lo = (unsigned)v, hi = (unsigned)(v >> 32);
    union { unsigned u; float f; } a0, a1, b0, b1;
    a0.u = lo << 16; a1.u = lo & 0xffff0000u;
    b0.u = hi << 16; b1.u = hi & 0xffff0000u;
    const v2f a = { a0.f, a1.f }, b = { b0.f, b1.f };
    const v2f w2 = { w, w };
#ifdef HAVE_EW_FMA
    acc[0] = __builtin_elementwise_fma(a, w2, acc[0]);
    acc[1] = __builtin_elementwise_fma(b, w2, acc[1]);
#else
    acc[0] += a * w2;
    acc[1] += b * w2;
#endif
}

template<int CH>
__device__ __forceinline__ void gchunk(const unsigned long long* __restrict__ tile,
                                       const int* ji, const float* jw,
                                       v2f acc[4][2])
{
    unsigned long long t[CH][4];
    #pragma unroll
    for (int k = 0; k < CH; ++k) {
        #pragma unroll
        for (int q = 0; q < 4; ++q) t[k][q] = tile[q * NC + ji[k]];
    }
    #pragma unroll
    for (int k = 0; k < CH; ++k) {
        #pragma unroll
        for (int q = 0; q < 4; ++q) fmaq(t[k][q], jw[k], acc[q]);
    }
}

template<int K>
__device__ __forceinline__ void gacc(const unsigned long long* __restrict__ tile,
                                     const int* ji, const float* jw, const float jb,
                                     v2f acc[4][2])
{
    #pragma unroll
    for (int q = 0; q < 4; ++q) { acc[q][0] = (v2f){ jb, jb }; acc[q][1] = (v2f){ jb, jb }; }
    if (K == 8) {
        gchunk<4>(tile, ji,     jw,     acc);
        gchunk<4>(tile, ji + 4, jw + 4, acc);
    } else {
        gchunk<K>(tile, ji, jw, acc);
    }
}

// ================= persistent fused kernel =================

// One sparse layer over the block's 16 rows (in-place in LDS).
// FINAL: relu -> global out, no writeback.
template<int K, bool FOLD, bool STATS, bool FINAL>
__device__ __forceinline__ void pphase(
    unsigned long long* __restrict__ tile,
    const float* __restrict__ s_sc, const float* __restrict__ s_sh,
    const int* __restrict__ idx, const float* __restrict__ W,
    const float* __restrict__ bias,
    const int tid, const int row0, const int rep,
    float* __restrict__ psum, float* __restrict__ psq,
    float* __restrict__ fout)
{
    unsigned long long o[PNSLOT][4];
    float st1[PNSLOT], st2[PNSLOT];
    #pragma unroll
    for (int s = 0; s < PNSLOT; ++s) {
        const int j = tid + s * PTHREADS;
        if (j < NC) {
            int ji[K]; float jw[K];
            float jb = bias[j];
            #pragma unroll
            for (int k = 0; k < K; ++k) {
                const int   c = idx[K * j + k];
                const float w = W[K * j + k];
                ji[k] = c;
                if (FOLD) { jw[k] = w * s_sc[c]; jb = fmaf(w, s_sh[c], jb); }
                else      { jw[k] = w; }
            }
            v2f acc[4][2];
            gacc<K>(tile, ji, jw, jb, acc);
            if (FINAL) {
                #pragma unroll
                for (int q = 0; q < 4; ++q) {
                    fout[(size_t)(row0 + 4 * q + 0) * NC + j] = fmaxf(acc[q][0].x, 0.0f);
                    fout[(size_t)(row0 + 4 * q + 1) * NC + j] = fmaxf(acc[q][0].y, 0.0f);
                    fout[(size_t)(row0 + 4 * q + 2) * NC + j] = fmaxf(acc[q][1].x, 0.0f);
                    fout[(size_t)(row0 + 4 * q + 3) * NC + j] = fmaxf(acc[q][1].y, 0.0f);
                }
            } else {
                float s1 = 0.0f, s2 = 0.0f;
                #pragma unroll
                for (int q = 0; q < 4; ++q) {
                    const float u0 = gelu_f(acc[q][0].x), u1 = gelu_f(acc[q][0].y);
                    const float u2 = gelu_f(acc[q][1].x), u3 = gelu_f(acc[q][1].y);
                    if (STATS) {
                        s1 += (u0 + u1) + (u2 + u3);
                        s2 = fmaf(u0, u0, fmaf(u1, u1, fmaf(u2, u2, fmaf(u3, u3, s2))));
                    }
                    o[s][q] = pack4(u0, u1, u2, u3);
                }
                st1[s] = s1; st2[s] = s2;
            }
        }
    }
    if (FINAL) return;
    __syncthreads();                       // all gathers of old tile done
    #pragma unroll
    for (int s = 0; s < PNSLOT; ++s) {
        const int j = tid + s * PTHREADS;
        if (j < NC) {
            #pragma unroll
            for (int q = 0; q < 4; ++q) tile[q * NC + j] = o[s][q];
            if (STATS) {
                atomicAdd(&psum[rep * NC + j], st1[s]);
                atomicAdd(&psq [rep * NC + j], st2[s]);
            }
        }
    }
    __syncthreads();                       // writeback visible + atomics drained (vmcnt)
}

// BN boundary: arrive -> last block finalizes scale/shift -> release flag ->
// all blocks load scale/shift to LDS. Single-thread sleep-poll (not grid.sync).
__device__ __forceinline__ void bn_barrier(
    const int tid, const int bno,
    const float* __restrict__ psum, const float* __restrict__ psq,
    const float* __restrict__ gamma, const float* __restrict__ beta,
    unsigned long long* __restrict__ scshG,
    unsigned* __restrict__ arrive, unsigned* __restrict__ flag,
    float* __restrict__ s_sc, float* __restrict__ s_sh, int* __restrict__ s_last)
{
    if (tid == 0) {
        __threadfence();
        const unsigned t = __hip_atomic_fetch_add(&arrive[bno], 1u,
                              __ATOMIC_ACQ_REL, __HIP_MEMORY_SCOPE_AGENT);
        *s_last = (t == (unsigned)(NBLK - 1));
    }
    __syncthreads();
    if (*s_last) {
        for (int j = tid; j < NC; j += PTHREADS) {
            float s1 = 0.0f, s2 = 0.0f;
            #pragma unroll
            for (int r = 0; r < NREP; ++r) {
                s1 += __hip_atomic_load(&psum[r * NC + j], __ATOMIC_RELAXED, __HIP_MEMORY_SCOPE_AGENT);
                s2 += __hip_atomic_load(&psq [r * NC + j], __ATOMIC_RELAXED, __HIP_MEMORY_SCOPE_AGENT);
            }
            const float m   = s1 * INV_B;
            const float var = fmaf(-m, m, s2 * INV_B);
            const float sc  = gamma[j] * rsqrtf(var + EPS);
            const float sh  = fmaf(-m, sc, beta[j]);
            __hip_atomic_store(&scshG[j], pack_f2(sc, sh),
                               __ATOMIC_RELAXED, __HIP_MEMORY_SCOPE_AGENT);
        }
        __syncthreads();                   // all scsh stores issued+drained
        if (tid == 0)
            __hip_atomic_store(&flag[bno], 1u, __ATOMIC_RELEASE, __HIP_MEMORY_SCOPE_AGENT);
    } else if (tid == 0) {
        while (__hip_atomic_load(&flag[bno], __ATOMIC_ACQUIRE, __HIP_MEMORY_SCOPE_AGENT) == 0u)
            __builtin_amdgcn_s_sleep(32);
    }
    __syncthreads();
    for (int j = tid; j < NC; j += PTHREADS) {
        float sc, sh;
        unpack_f2(__hip_atomic_load(&scshG[j], __ATOMIC_RELAXED, __HIP_MEMORY_SCOPE_AGENT), sc, sh);
        s_sc[j] = sc; s_sh[j] = sh;
    }
    __syncthreads();
}

__global__ __launch_bounds__(PTHREADS, 4)
void fusedp(const float* __restrict__ x,
            const int* __restrict__ idx1, const float* __restrict__ W1, const float* __restrict__ b1,
            const int* __restrict__ idx2, const float* __restrict__ W2, const float* __restrict__ b2,
            const int* __restrict__ idx3, const float* __restrict__ W3, const float* __restrict__ b3,
            const float* __restrict__ g2, const float* __restrict__ be2,
            const float* __restrict__ g3, const float* __restrict__ be3,
            float* __restrict__ out,
            float* __restrict__ stats,             // 6*NREP*NC floats
            unsigned long long* __restrict__ scsh, // 3*NC packed {sc,sh}
            unsigned* __restrict__ sync)           // arrive[0..3], flag[4..7]
{
    __shared__ unsigned long long tile[4 * NC];    // 25088 B
    __shared__ float s_sc[NC], s_sh[NC];           //  6272 B
    __shared__ int s_last;
    const int tid  = threadIdx.x;
    const int row0 = blockIdx.x * TRB;
    const int rep  = blockIdx.x & (NREP - 1);

    float* psumA = stats;                 float* psqA = psumA + NREP * NC;
    float* psumB = psqA  + NREP * NC;     float* psqB = psumB + NREP * NC;
    float* psumC = psqB  + NREP * NC;     float* psqC = psumC + NREP * NC;
    unsigned* arrive = sync;
    unsigned* flag   = sync + 4;

    // ---- stage x -> quad bf16 tile ----
    #pragma unroll
    for (int s = 0; s < PNSLOT; ++s) {
        const int c = tid + s * PTHREADS;
        if (c < NC) {
            #pragma unroll
            for (int q = 0; q < 4; ++q) {
                const size_t base = (size_t)(row0 + 4 * q) * NC + c;
                tile[q * NC + c] = pack4(x[base], x[base + NC], x[base + 2 * NC], x[base + 3 * NC]);
            }
        }
    }
    __syncthreads();

    // L1: sp1 -> gelu (in-place)
    pphase<2, false, false, false>(tile, s_sc, s_sh, idx1, W1, b1, tid, row0, rep,
                                   nullptr, nullptr, nullptr);
    // L2a: sp2 -> gelu + bn2a stats
    pphase<4, false, true, false>(tile, s_sc, s_sh, idx2, W2, b2, tid, row0, rep,
                                  psumA, psqA, nullptr);
    bn_barrier(tid, 0, psumA, psqA, g2, be2, scsh,           arrive, flag, s_sc, s_sh, &s_last);
    // L3: fold bn2a -> sp3 -> gelu + bn3 stats
    pphase<8, true, true, false>(tile, s_sc, s_sh, idx3, W3, b3, tid, row0, rep,
                                 psumB, psqB, nullptr);
    bn_barrier(tid, 1, psumB, psqB, g3, be3, scsh + NC,      arrive, flag, s_sc, s_sh, &s_last);
    // L2b: fold bn3 -> sp2 -> gelu + bn2b stats
    pphase<4, true, true, false>(tile, s_sc, s_sh, idx2, W2, b2, tid, row0, rep,
                                 psumC, psqC, nullptr);
    bn_barrier(tid, 2, psumC, psqC, g2, be2, scsh + 2 * NC,  arrive, flag, s_sc, s_sh, &s_last);
    // L1b: fold bn2b -> sp1 -> relu -> out
    pphase<2, true, false, true>(tile, s_sc, s_sh, idx1, W1, b1, tid, row0, rep,
                                 nullptr, nullptr, out);
}

// ================= fallback: proven 4-kernel pipeline (185 us) =================

__device__ __forceinline__ void fmaq2(const unsigned long long v, const float w, v2f acc[2]) {
    fmaq(v, w, acc);
}

__global__ __launch_bounds__(FTHREADS, 6)
void k12(const float* __restrict__ x,
         const int* __restrict__ idx1, const float* __restrict__ W1, const float* __restrict__ b1,
         const int* __restrict__ idx2, const float* __restrict__ W2, const float* __restrict__ b2,
         unsigned long long* __restrict__ outr,
         float* __restrict__ ssum, float* __restrict__ ssq)
{
    __shared__ unsigned long long tileX[4 * NC];
    __shared__ unsigned long long tileH[4 * NC];
    const int tid  = threadIdx.x;
    const int row0 = blockIdx.x * TRB;

    #pragma unroll
    for (int slot = 0; slot < FNSLOT; ++slot) {
        const int c = tid + slot * FTHREADS;
        if (c < NC) {
            #pragma unroll
            for (int q = 0; q < 4; ++q) {
                const size_t base = (size_t)(row0 + 4 * q) * NC + c;
                tileX[q * NC + c] = pack4(x[base], x[base + NC], x[base + 2 * NC], x[base + 3 * NC]);
            }
        }
    }
    __syncthreads();

    #pragma unroll
    for (int slot = 0; slot < FNSLOT; ++slot) {
        const int j = tid + slot * FTHREADS;
        if (j < NC) {
            const int   c0 = idx1[2 * j], c1 = idx1[2 * j + 1];
            const float w0 = W1[2 * j],   w1 = W1[2 * j + 1], bb = b1[j];
            #pragma unroll
            for (int q = 0; q < 4; ++q) {
                v2f acc[2] = { { bb, bb }, { bb, bb } };
                fmaq2(tileX[q * NC + c0], w0, acc);
                fmaq2(tileX[q * NC + c1], w1, acc);
                tileH[q * NC + j] = pack4(gelu_f(acc[0].x), gelu_f(acc[0].y),
                                          gelu_f(acc[1].x), gelu_f(acc[1].y));
            }
        }
    }
    __syncthreads();

    const int rep = blockIdx.x & (NREP - 1);
    unsigned long long* dst = outr + (size_t)blockIdx.x * 4 * NC;
    #pragma unroll
    for (int slot = 0; slot < FNSLOT; ++slot) {
        const int j = tid + slot * FTHREADS;
        if (j < NC) {
            int ji[4]; float jw[4];
            #pragma unroll
            for (int k = 0; k < 4; ++k) { ji[k] = idx2[4 * j + k]; jw[k] = W2[4 * j + k]; }
            const float jb = b2[j];
            float s1 = 0.0f, s2 = 0.0f;
            #pragma unroll
            for (int q = 0; q < 4; ++q) {
                v2f acc[2] = { { jb, jb }, { jb, jb } };
                #pragma unroll
                for (int k = 0; k < 4; ++k) fmaq2(tileH[q * NC + ji[k]], jw[k], acc);
                const float u0 = gelu_f(acc[0].x), u1 = gelu_f(acc[0].y);
                const float u2 = gelu_f(acc[1].x), u3 = gelu_f(acc[1].y);
                s1 += (u0 + u1) + (u2 + u3);
                s2 = fmaf(u0, u0, fmaf(u1, u1, fmaf(u2, u2, fmaf(u3, u3, s2))));
                dst[q * NC + j] = pack4(u0, u1, u2, u3);
            }
            atomicAdd(&ssum[rep * NC + j], s1);
            atomicAdd(&ssq[rep * NC + j],  s2);
        }
    }
}

template<int K, bool FINAL>
__global__ __launch_bounds__(FTHREADS, 8)
void kbn(const unsigned long long* __restrict__ inr,
         const int* __restrict__ idx, const float* __restrict__ W, const float* __restrict__ bias,
         const float* __restrict__ gamma, const float* __restrict__ beta,
         const float* __restrict__ psum, const float* __restrict__ psq,
         unsigned long long* __restrict__ outr, float* __restrict__ fout,
         float* __restrict__ ssum, float* __restrict__ ssq)
{
    __shared__ unsigned long long tile[4 * NC];
    __shared__ float s_sc[NC], s_sh[NC];
    const int tid  = threadIdx.x;
    const int row0 = blockIdx.x * TRB;

    {
        const float4* src = (const float4*)(inr + (size_t)blockIdx.x * 4 * NC);
        float4*       dstl = (float4*)tile;
        for (int i = tid; i < 4 * NC / 2; i += FTHREADS) stage16(src + i, dstl + i);
    }
    for (int j = tid; j < NC; j += FTHREADS) {
        float s1 = 0.0f, s2 = 0.0f;
        #pragma unroll
        for (int r = 0; r < NREP; ++r) { s1 += psum[r * NC + j]; s2 += psq[r * NC + j]; }
        const float m   = s1 * INV_B;
        const float var = fmaf(-m, m, s2 * INV_B);
        const float sc  = gamma[j] * rsqrtf(var + EPS);
        s_sc[j] = sc;
        s_sh[j] = fmaf(-m, sc, beta[j]);
    }
    __syncthreads();

    const int rep = blockIdx.x & (NREP - 1);
    unsigned long long* dst = FINAL ? nullptr : (outr + (size_t)blockIdx.x * 4 * NC);
    #pragma unroll
    for (int slot = 0; slot < FNSLOT; ++slot) {
        const int j = tid + slot * FTHREADS;
        if (j < NC) {
            int ji[K]; float jw[K];
            float jb = bias[j];
            #pragma unroll
            for (int k = 0; k < K; ++k) {
                const int   c = idx[K * j + k];
                const float w = W[K * j + k];
                ji[k] = c; jw[k] = w * s_sc[c]; jb = fmaf(w, s_sh[c], jb);
            }
            float s1 = 0.0f, s2 = 0.0f;
            #pragma unroll
            for (int q = 0; q < 4; ++q) {
                v2f acc[2] = { { jb, jb }, { jb, jb } };
                #pragma unroll
                for (int k = 0; k < K; ++k) fmaq2(tile[q * NC + ji[k]], jw[k], acc);
                if (FINAL) {
                    fout[(size_t)(row0 + 4 * q + 0) * NC + j] = fmaxf(acc[0].x, 0.0f);
                    fout[(size_t)(row0 + 4 * q + 1) * NC + j] = fmaxf(acc[0].y, 0.0f);
                    fout[(size_t)(row0 + 4 * q + 2) * NC + j] = fmaxf(acc[1].x, 0.0f);
                    fout[(size_t)(row0 + 4 * q + 3) * NC + j] = fmaxf(acc[1].y, 0.0f);
                } else {
                    const float u0 = gelu_f(acc[0].x), u1 = gelu_f(acc[0].y);
                    const float u2 = gelu_f(acc[1].x), u3 = gelu_f(acc[1].y);
                    s1 += (u0 + u1) + (u2 + u3);
                    s2 = fmaf(u0, u0, fmaf(u1, u1, fmaf(u2, u2, fmaf(u3, u3, s2))));
                    dst[q * NC + j] = pack4(u0, u1, u2, u3);
                }
            }
            if (!FINAL) {
                atomicAdd(&ssum[rep * NC + j], s1);
                atomicAdd(&ssq[rep * NC + j],  s2);
            }
        }
    }
}

extern "C" void kernel_launch(void* const* d_in, const int* in_sizes, int n_in,
                              void* d_out, int out_size, void* d_ws, size_t ws_size,
                              hipStream_t stream)
{
    const float* x    = (const float*)d_in[0];
    const int*   idx1 = (const int*)  d_in[1];
    const float* W1   = (const float*)d_in[2];
    const float* b1   = (const float*)d_in[3];
    const int*   idx2 = (const int*)  d_in[4];
    const float* W2   = (const float*)d_in[5];
    const float* b2   = (const float*)d_in[6];
    const int*   idx3 = (const int*)  d_in[7];
    const float* W3   = (const float*)d_in[8];
    const float* b3   = (const float*)d_in[9];
    const float* g2   = (const float*)d_in[10];
    const float* be2  = (const float*)d_in[11];
    const float* g3   = (const float*)d_in[12];
    const float* be3  = (const float*)d_in[13];
    float* out = (float*)d_out;

    const size_t QN = (size_t)NBLK * 4 * NC;       // u64 elems per fallback intermediate
    unsigned long long* r0 = (unsigned long long*)d_ws;
    unsigned long long* r1 = r0 + QN;
    float* stats = (float*)(r1 + QN);              // 6*NREP*NC floats
    unsigned* syncw = (unsigned*)(stats + 6 * NREP * NC);   // 8 u32
    unsigned long long* scsh = (unsigned long long*)(syncw + 8); // 3*NC u64

    // zero stats + sync words each launch (graph-replay safe)
    hipMemsetAsync(stats, 0, 6 * NREP * NC * sizeof(float) + 8 * sizeof(unsigned), stream);

    // ---- preferred: single persistent kernel with custom BN barriers ----
    void* args[] = {
        (void*)&x,
        (void*)&idx1, (void*)&W1, (void*)&b1,
        (void*)&idx2, (void*)&W2, (void*)&b2,
        (void*)&idx3, (void*)&W3, (void*)&b3,
        (void*)&g2, (void*)&be2, (void*)&g3, (void*)&be3,
        (void*)&out, (void*)&stats, (void*)&scsh, (void*)&syncw
    };
    const hipError_t err = hipLaunchCooperativeKernel(
        (const void*)fusedp, dim3(NBLK), dim3(PTHREADS), args, 0, stream);
    if (err == hipSuccess) return;

    // ---- fallback: proven 4-kernel pipeline ----
    float* sum2a = stats;              float* ssq2a = sum2a + NREP * NC;
    float* sum3  = ssq2a + NREP * NC;  float* ssq3  = sum3  + NREP * NC;
    float* sum2b = ssq3  + NREP * NC;  float* ssq2b = sum2b + NREP * NC;

    const dim3 grid(NBLK), blk(FTHREADS);
    k12<<<grid, blk, 0, stream>>>(x, idx1, W1, b1, idx2, W2, b2, r0, sum2a, ssq2a);
    kbn<8, false><<<grid, blk, 0, stream>>>(
        r0, idx3, W3, b3, g2, be2, sum2a, ssq2a, r1, nullptr, sum3, ssq3);
    kbn<4, false><<<grid, blk, 0, stream>>>(
        r1, idx2, W2, b2, g3, be3, sum3, ssq3, r0, nullptr, sum2b, ssq2b);
    kbn<2, true><<<grid, blk, 0, stream>>>(
        r0, idx1, W1, b1, g2, be2, sum2b, ssq2b, nullptr, out, nullptr, nullptr);
}

// Round 9
// 185.663 us; speedup vs baseline: 3.3855x; 3.3855x over previous
//
#include <hip/hip_runtime.h>
#include <math.h>

static constexpr int BROWS   = 16384;
static constexpr int NC      = 784;
static constexpr int TRB     = 16;              // rows per tile/block
static constexpr int THREADS = 512;
static constexpr int NBLK    = BROWS / TRB;     // 1024 blocks
static constexpr int NSLOT   = 2;               // ceil(784/512) column slots per thread
static constexpr int NREP    = 4;               // replicated stat accumulators
static constexpr float EPS   = 1e-5f;
static constexpr float INV_B = 1.0f / (float)BROWS;

#if defined(__has_builtin)
#if __has_builtin(__builtin_amdgcn_global_load_lds)
#define HAVE_ASYNC_LDS 1
#endif
#if __has_builtin(__builtin_amdgcn_rcpf)
#define HAVE_RCPF 1
#endif
#if __has_builtin(__builtin_elementwise_fma)
#define HAVE_EW_FMA 1
#endif
#endif

typedef float v2f __attribute__((ext_vector_type(2)));

__device__ __forceinline__ void stage16(const float4* g, float4* l) {
#ifdef HAVE_ASYNC_LDS
    __builtin_amdgcn_global_load_lds(
        (const __attribute__((address_space(1))) void*)g,
        (__attribute__((address_space(3))) void*)l, 16, 0, 0);
#else
    *l = *g;
#endif
}

// ---- bf16 helpers (raw u16 storage; RNE convert) ----
__device__ __forceinline__ unsigned short f2b(float f) {
    union { float f; unsigned u; } v; v.f = f;
    const unsigned r = v.u + 0x7fffu + ((v.u >> 16) & 1u);
    return (unsigned short)(r >> 16);
}
__device__ __forceinline__ unsigned pack2(float lo, float hi) {
    return (unsigned)f2b(lo) | ((unsigned)f2b(hi) << 16);
}
__device__ __forceinline__ unsigned long long pack4(float a, float b, float c, float d) {
    return (unsigned long long)pack2(a, b) | ((unsigned long long)pack2(c, d) << 32);
}
__device__ __forceinline__ float fast_rcp(float x) {
#ifdef HAVE_RCPF
    return __builtin_amdgcn_rcpf(x);
#else
    return 1.0f / x;
#endif
}

// tanh-form gelu (max |err| ~3e-4, far under the 0.2625 budget), branchless.
__device__ __forceinline__ float gelu_f(float x) {
    const float u  = x * x;
    const float z  = x * fmaf(0.0356774081f, u, 0.7978845608f);
    const float e  = __expf(2.0f * z);            // e^{2z}
    const float r  = fast_rcp(e + 1.0f);
    const float t  = fmaf(-2.0f, r, 1.0f);        // tanh(z)
    const float hx = 0.5f * x;
    return fmaf(hx, t, hx);
}

// u64 = 4 bf16 rows of one column (rows 4q..4q+3). Unpack to 2x v2f and FMA
// with packed v_pk_fma_f32.
__device__ __forceinline__ void fmaq(const unsigned long long v, const float w, v2f acc[2]) {
    const unsigned lo = (unsigned)v, hi = (unsigned)(v >> 32);
    union { unsigned u; float f; } a0, a1, b0, b1;
    a0.u = lo << 16; a1.u = lo & 0xffff0000u;
    b0.u = hi << 16; b1.u = hi & 0xffff0000u;
    const v2f a = { a0.f, a1.f }, b = { b0.f, b1.f };
    const v2f w2 = { w, w };
#ifdef HAVE_EW_FMA
    acc[0] = __builtin_elementwise_fma(a, w2, acc[0]);
    acc[1] = __builtin_elementwise_fma(b, w2, acc[1]);
#else
    acc[0] += a * w2;
    acc[1] += b * w2;
#endif
}

// ---------------- K_A: fused L1 -> gelu -> L2 -> gelu (+ bn2a stats) ----------------
// SINGLE 25 KB tile (was 2 tiles / 50 KB): L1 outputs are computed into 16
// registers, then written back in-place after a barrier (WAR-safe).
// launch_bounds(512,8) -> 4 blocks/CU -> 1024 blocks = exactly one block-round
// on 256 CUs: kills the 256-block 1/3-occupancy tail the 2-tile version had.
__global__ __launch_bounds__(THREADS, 8)
void k12(const float* __restrict__ x,
         const int* __restrict__ idx1, const float* __restrict__ W1, const float* __restrict__ b1,
         const int* __restrict__ idx2, const float* __restrict__ W2, const float* __restrict__ b2,
         unsigned long long* __restrict__ outr,
         float* __restrict__ ssum, float* __restrict__ ssq)
{
    __shared__ unsigned long long tile[4 * NC];    // 25088 B
    const int tid  = threadIdx.x;
    const int row0 = blockIdx.x * TRB;

    // stage x (fp32 row-major) -> quad bf16 tile (coalesced dword reads per row)
    #pragma unroll
    for (int slot = 0; slot < NSLOT; ++slot) {
        const int c = tid + slot * THREADS;
        if (c < NC) {
            #pragma unroll
            for (int q = 0; q < 4; ++q) {
                const size_t base = (size_t)(row0 + 4 * q) * NC + c;
                tile[q * NC + c] = pack4(x[base], x[base + NC], x[base + 2 * NC], x[base + 3 * NC]);
            }
        }
    }
    __syncthreads();

    // L1 (K=2): compute into registers (tile only READ here)
    unsigned long long o[NSLOT][4];
    #pragma unroll
    for (int slot = 0; slot < NSLOT; ++slot) {
        const int j = tid + slot * THREADS;
        if (j < NC) {
            const int   c0 = idx1[2 * j], c1 = idx1[2 * j + 1];
            const float w0 = W1[2 * j],   w1 = W1[2 * j + 1], bb = b1[j];
            #pragma unroll
            for (int q = 0; q < 4; ++q) {
                v2f acc[2] = { { bb, bb }, { bb, bb } };
                fmaq(tile[q * NC + c0], w0, acc);
                fmaq(tile[q * NC + c1], w1, acc);
                o[slot][q] = pack4(gelu_f(acc[0].x), gelu_f(acc[0].y),
                                   gelu_f(acc[1].x), gelu_f(acc[1].y));
            }
        }
    }
    __syncthreads();                               // all L1 reads of tile done
    #pragma unroll
    for (int slot = 0; slot < NSLOT; ++slot) {
        const int j = tid + slot * THREADS;
        if (j < NC) {
            #pragma unroll
            for (int q = 0; q < 4; ++q) tile[q * NC + j] = o[slot][q];
        }
    }
    __syncthreads();

    // L2 (K=4) + gelu + stats + quad global store
    const int rep = blockIdx.x & (NREP - 1);
    unsigned long long* dst = outr + (size_t)blockIdx.x * 4 * NC;
    #pragma unroll
    for (int slot = 0; slot < NSLOT; ++slot) {
        const int j = tid + slot * THREADS;
        if (j < NC) {
            int ji[4]; float jw[4];
            #pragma unroll
            for (int k = 0; k < 4; ++k) { ji[k] = idx2[4 * j + k]; jw[k] = W2[4 * j + k]; }
            const float jb = b2[j];
            float s1 = 0.0f, s2 = 0.0f;
            #pragma unroll
            for (int q = 0; q < 4; ++q) {
                v2f acc[2] = { { jb, jb }, { jb, jb } };
                #pragma unroll
                for (int k = 0; k < 4; ++k) fmaq(tile[q * NC + ji[k]], jw[k], acc);
                const float u0 = gelu_f(acc[0].x), u1 = gelu_f(acc[0].y);
                const float u2 = gelu_f(acc[1].x), u3 = gelu_f(acc[1].y);
                s1 += (u0 + u1) + (u2 + u3);
                s2 = fmaf(u0, u0, fmaf(u1, u1, fmaf(u2, u2, fmaf(u3, u3, s2))));
                dst[q * NC + j] = pack4(u0, u1, u2, u3);
            }
            atomicAdd(&ssum[rep * NC + j], s1);
            atomicAdd(&ssq[rep * NC + j],  s2);
        }
    }
}

// -------- K_B/C/D: fold prev BN into weights -> sparse -> act (+ stats) --------
// Byte-identical to the proven 185.4us R0 version.
template<int K, bool FINAL>
__global__ __launch_bounds__(THREADS, 8)
void kbn(const unsigned long long* __restrict__ inr,
         const int* __restrict__ idx, const float* __restrict__ W, const float* __restrict__ bias,
         const float* __restrict__ gamma, const float* __restrict__ beta,
         const float* __restrict__ psum, const float* __restrict__ psq,
         unsigned long long* __restrict__ outr, float* __restrict__ fout,
         float* __restrict__ ssum, float* __restrict__ ssq)
{
    __shared__ unsigned long long tile[4 * NC];    // 25088 B
    __shared__ float s_sc[NC], s_sh[NC];           //  6272 B
    const int tid  = threadIdx.x;
    const int row0 = blockIdx.x * TRB;

    {   // async DMA of the contiguous quad region (lane-linear dst)
        const float4* src = (const float4*)(inr + (size_t)blockIdx.x * 4 * NC);
        float4*       dstl = (float4*)tile;
        for (int i = tid; i < 4 * NC / 2; i += THREADS) stage16(src + i, dstl + i);
    }
    // finalize previous BN into scale/shift (L2-hot; overlaps the DMA)
    for (int j = tid; j < NC; j += THREADS) {
        float s1 = 0.0f, s2 = 0.0f;
        #pragma unroll
        for (int r = 0; r < NREP; ++r) { s1 += psum[r * NC + j]; s2 += psq[r * NC + j]; }
        const float m   = s1 * INV_B;
        const float var = fmaf(-m, m, s2 * INV_B);
        const float sc  = gamma[j] * rsqrtf(var + EPS);
        s_sc[j] = sc;
        s_sh[j] = fmaf(-m, sc, beta[j]);
    }
    __syncthreads();   // drains DMA + publishes sc/sh

    const int rep = blockIdx.x & (NREP - 1);
    unsigned long long* dst = FINAL ? nullptr : (outr + (size_t)blockIdx.x * 4 * NC);
    #pragma unroll
    for (int slot = 0; slot < NSLOT; ++slot) {
        const int j = tid + slot * THREADS;
        if (j < NC) {
            int ji[K]; float jw[K];
            float jb = bias[j];
            #pragma unroll
            for (int k = 0; k < K; ++k) {
                const int   c = idx[K * j + k];
                const float w = W[K * j + k];
                ji[k] = c; jw[k] = w * s_sc[c]; jb = fmaf(w, s_sh[c], jb);
            }
            float s1 = 0.0f, s2 = 0.0f;
            #pragma unroll
            for (int q = 0; q < 4; ++q) {
                v2f acc[2] = { { jb, jb }, { jb, jb } };
                #pragma unroll
                for (int k = 0; k < K; ++k) fmaq(tile[q * NC + ji[k]], jw[k], acc);
                if (FINAL) {
                    fout[(size_t)(row0 + 4 * q + 0) * NC + j] = fmaxf(acc[0].x, 0.0f);
                    fout[(size_t)(row0 + 4 * q + 1) * NC + j] = fmaxf(acc[0].y, 0.0f);
                    fout[(size_t)(row0 + 4 * q + 2) * NC + j] = fmaxf(acc[1].x, 0.0f);
                    fout[(size_t)(row0 + 4 * q + 3) * NC + j] = fmaxf(acc[1].y, 0.0f);
                } else {
                    const float u0 = gelu_f(acc[0].x), u1 = gelu_f(acc[0].y);
                    const float u2 = gelu_f(acc[1].x), u3 = gelu_f(acc[1].y);
                    s1 += (u0 + u1) + (u2 + u3);
                    s2 = fmaf(u0, u0, fmaf(u1, u1, fmaf(u2, u2, fmaf(u3, u3, s2))));
                    dst[q * NC + j] = pack4(u0, u1, u2, u3);
                }
            }
            if (!FINAL) {
                atomicAdd(&ssum[rep * NC + j], s1);
                atomicAdd(&ssq[rep * NC + j],  s2);
            }
        }
    }
}

extern "C" void kernel_launch(void* const* d_in, const int* in_sizes, int n_in,
                              void* d_out, int out_size, void* d_ws, size_t ws_size,
                              hipStream_t stream)
{
    const float* x    = (const float*)d_in[0];
    const int*   idx1 = (const int*)  d_in[1];
    const float* W1   = (const float*)d_in[2];
    const float* b1   = (const float*)d_in[3];
    const int*   idx2 = (const int*)  d_in[4];
    const float* W2   = (const float*)d_in[5];
    const float* b2   = (const float*)d_in[6];
    const int*   idx3 = (const int*)  d_in[7];
    const float* W3   = (const float*)d_in[8];
    const float* b3   = (const float*)d_in[9];
    const float* g2   = (const float*)d_in[10];
    const float* be2  = (const float*)d_in[11];
    const float* g3   = (const float*)d_in[12];
    const float* be3  = (const float*)d_in[13];
    float* out = (float*)d_out;

    const size_t QN = (size_t)NBLK * 4 * NC;       // u64 elems per intermediate
    // Quad-layout bf16 ping-pong:
    //   k12      : r x  -> w r0
    //   kbn<8>   : r r0 -> w r1
    //   kbn<4>   : r r1 -> w r0
    //   kbn<2,F> : r r0 -> w out (fp32 row-major)
    unsigned long long* r0 = (unsigned long long*)d_ws;
    unsigned long long* r1 = r0 + QN;
    float* p = (float*)(r1 + QN);
    float* sum2a = p; p += NREP * NC;  float* ssq2a = p; p += NREP * NC;
    float* sum3  = p; p += NREP * NC;  float* ssq3  = p; p += NREP * NC;
    float* sum2b = p; p += NREP * NC;  float* ssq2b = p; p += NREP * NC;

    hipMemsetAsync(sum2a, 0, 6 * NREP * NC * sizeof(float), stream);

    const dim3 grid(NBLK), blk(THREADS);

    k12<<<grid, blk, 0, stream>>>(x, idx1, W1, b1, idx2, W2, b2, r0, sum2a, ssq2a);
    kbn<8, false><<<grid, blk, 0, stream>>>(
        r0, idx3, W3, b3, g2, be2, sum2a, ssq2a, r1, nullptr, sum3, ssq3);
    kbn<4, false><<<grid, blk, 0, stream>>>(
        r1, idx2, W2, b2, g3, be3, sum3, ssq3, r0, nullptr, sum2b, ssq2b);
    kbn<2, true><<<grid, blk, 0, stream>>>(
        r0, idx1, W1, b1, g2, be2, sum2b, ssq2b, nullptr, out, nullptr, nullptr);
}